// Round 1
// baseline (153.306 us; speedup 1.0000x reference)
//
#include <hip/hip_runtime.h>
#include <hip/hip_bf16.h>
#include <stdint.h>

typedef __bf16 bf16x8 __attribute__((ext_vector_type(8)));
typedef float f32x4 __attribute__((ext_vector_type(4)));

constexpr int Bn = 8, Ln = 4096, Dn = 512, Hn = 512;
constexpr int Mrows = Bn * Ln;                  // 32768
constexpr int CHUNK = 64, NCHUNK = Ln / CHUNK;  // 64 chunks of 64

// ---------------------------------------------------------------- prep
__global__ __launch_bounds__(256) void prep_kernel(
    const float* __restrict__ W_B, const float* __restrict__ W_C,
    const float* __restrict__ W_out, const float* __restrict__ b_B,
    const float* __restrict__ b_C,
    __hip_bfloat16* __restrict__ WbcT, __hip_bfloat16* __restrict__ WoT,
    float* __restrict__ bbc)
{
    int id = blockIdx.x * 256 + threadIdx.x;   // grid covers 1024*512
    {
        int n = id >> 9, k = id & 511;
        float w = (n < Hn) ? W_B[k * Hn + n] : W_C[k * Hn + (n - Hn)];
        WbcT[id] = __float2bfloat16(w);        // WbcT[n][k] = W[k][n]
    }
    if (id < Hn * Hn) {
        int n = id >> 9, k = id & 511;
        WoT[id] = __float2bfloat16(W_out[k * Hn + n]);
    }
    if (id < 2 * Hn) bbc[id] = (id < Hn) ? b_B[id] : b_C[id - Hn];
}

// ---------------------------------------------------------------- layernorm
__global__ __launch_bounds__(256) void ln_kernel(
    const float* __restrict__ x, const float* __restrict__ gamma,
    const float* __restrict__ beta, __hip_bfloat16* __restrict__ xn)
{
    int row = blockIdx.x;
    const float2* xr = reinterpret_cast<const float2*>(x + (size_t)row * Dn);
    int t = threadIdx.x;
    float2 v = xr[t];
    float s = v.x + v.y;
    float s2 = v.x * v.x + v.y * v.y;
    #pragma unroll
    for (int off = 32; off; off >>= 1) {
        s  += __shfl_down(s, off);
        s2 += __shfl_down(s2, off);
    }
    __shared__ float ps[4], ps2[4];
    int wid = t >> 6, lane = t & 63;
    if (lane == 0) { ps[wid] = s; ps2[wid] = s2; }
    __syncthreads();
    float su = ps[0] + ps[1] + ps[2] + ps[3];
    float su2 = ps2[0] + ps2[1] + ps2[2] + ps2[3];
    float mu = su * (1.0f / Dn);
    float var = su2 * (1.0f / Dn) - mu * mu;
    float inv = rsqrtf(var + 1e-5f);
    int c0 = 2 * t;
    float y0 = (v.x - mu) * inv * gamma[c0]     + beta[c0];
    float y1 = (v.y - mu) * inv * gamma[c0 + 1] + beta[c0 + 1];
    __hip_bfloat162 o;
    o.x = __float2bfloat16(y0);
    o.y = __float2bfloat16(y1);
    reinterpret_cast<__hip_bfloat162*>(xn + (size_t)row * Dn)[t] = o;
}

// ---------------------------------------------------------------- GEMM
// C[M][N] = A[M][512] * BT[N][512]^T + bias   (A,BT bf16 row-major; acc fp32)
template <bool OUT_BF16>
__global__ __launch_bounds__(256) void gemm_kernel(
    const __hip_bfloat16* __restrict__ A,
    const __hip_bfloat16* __restrict__ BT,
    const float* __restrict__ bias,
    void* __restrict__ Cout, int M, int N)
{
    constexpr int K = 512, BM = 128, BN = 128, BK = 64;
    __shared__ unsigned short As[BM][BK];   // 16 KB
    __shared__ unsigned short Bs[BN][BK];   // 16 KB

    // XCD-bijective swizzle (grid % 8 == 0 for all our launches)
    int nwg = gridDim.x;
    int bid = blockIdx.x;
    int q = nwg >> 3;
    int bswz = (bid & 7) * q + (bid >> 3);
    int nb = N / BN;
    int bm = bswz / nb, bn = bswz % nb;
    int row0 = bm * BM, col0 = bn * BN;

    int tid = threadIdx.x;
    int w = tid >> 6, l = tid & 63;
    int wr = (w >> 1) * 64, wc = (w & 1) * 64;

    f32x4 acc[4][4] = {};

    int sr = (l >> 3);       // 0..7   row-within-segment
    int sc = (l & 7) * 8;    // 0..56  col (elements)

    for (int k0 = 0; k0 < K; k0 += BK) {
        __syncthreads();   // prior compute done before LDS overwrite
        #pragma unroll
        for (int t = 0; t < 4; ++t) {
            int s = w * 4 + t;           // 1KB segment id, wave-uniform
            int r = s * 8 + sr;
            const __hip_bfloat16* ga = A  + (size_t)(row0 + r) * K + k0 + sc;
            const __hip_bfloat16* gb = BT + (size_t)(col0 + r) * K + k0 + sc;
            __builtin_amdgcn_global_load_lds(
                (const __attribute__((address_space(1))) void*)(const void*)ga,
                (__attribute__((address_space(3))) void*)(void*)(&As[0][0] + s * 512),
                16, 0, 0);
            __builtin_amdgcn_global_load_lds(
                (const __attribute__((address_space(1))) void*)(const void*)gb,
                (__attribute__((address_space(3))) void*)(void*)(&Bs[0][0] + s * 512),
                16, 0, 0);
        }
        __syncthreads();   // compiler drains vmcnt before barrier

        #pragma unroll
        for (int kk = 0; kk < 2; ++kk) {
            bf16x8 af[4], bfr[4];
            #pragma unroll
            for (int i = 0; i < 4; ++i) {
                af[i]  = *reinterpret_cast<const bf16x8*>(
                             &As[wr + i * 16 + (l & 15)][kk * 32 + (l >> 4) * 8]);
                bfr[i] = *reinterpret_cast<const bf16x8*>(
                             &Bs[wc + i * 16 + (l & 15)][kk * 32 + (l >> 4) * 8]);
            }
            #pragma unroll
            for (int mi = 0; mi < 4; ++mi)
                #pragma unroll
                for (int ni = 0; ni < 4; ++ni)
                    acc[mi][ni] = __builtin_amdgcn_mfma_f32_16x16x32_bf16(
                        af[mi], bfr[ni], acc[mi][ni], 0, 0, 0);
        }
    }

    #pragma unroll
    for (int mi = 0; mi < 4; ++mi) {
        #pragma unroll
        for (int ni = 0; ni < 4; ++ni) {
            int col = col0 + wc + ni * 16 + (l & 15);
            float bv = bias[col];
            #pragma unroll
            for (int j = 0; j < 4; ++j) {
                int row = row0 + wr + mi * 16 + (l >> 4) * 4 + j;
                float v = acc[mi][ni][j] + bv;
                if (OUT_BF16)
                    ((__hip_bfloat16*)Cout)[(size_t)row * N + col] = __float2bfloat16(v);
                else
                    ((float*)Cout)[(size_t)row * N + col] = v;
            }
        }
    }
}

// ---------------------------------------------------------------- scan
// BC layout: [row][1024] bf16, Bt = cols 0..511, Ct = cols 512..1023
__global__ __launch_bounds__(256) void scan1_kernel(
    const __hip_bfloat16* __restrict__ BC, const float* __restrict__ Av,
    float* __restrict__ S)
{
    int blk = blockIdx.x;                       // Bn*NCHUNK*2 = 1024
    int hh = (blk & 1) * 256 + threadIdx.x;
    int c = (blk >> 1) & (NCHUNK - 1);
    int b = blk >> 7;
    float a = Av[hh];
    const __hip_bfloat16* p = BC + ((size_t)(b * Ln + c * CHUNK) * 1024) + hh;
    float s = 0.f;
    #pragma unroll 8
    for (int i = 0; i < CHUNK; ++i) {
        float bv = __bfloat162float(p[(size_t)i * 1024]);
        s = a * s + bv;
    }
    S[((size_t)b * NCHUNK + c) * Hn + hh] = s;
}

__global__ __launch_bounds__(256) void scan2_kernel(
    const float* __restrict__ S, const float* __restrict__ Av,
    float* __restrict__ carry)
{
    int id = blockIdx.x * 256 + threadIdx.x;    // Bn*Hn = 4096
    int hh = id & (Hn - 1), b = id >> 9;
    float a = Av[hh];
    float aG = a;
    #pragma unroll
    for (int i = 0; i < 6; ++i) aG *= aG;       // a^64
    float h = 0.f;
    const float* Sp = S + (size_t)b * NCHUNK * Hn + hh;
    float* cp = carry + (size_t)b * NCHUNK * Hn + hh;
    for (int c = 0; c < NCHUNK; ++c) {
        cp[(size_t)c * Hn] = h;                 // state entering chunk c
        h = aG * h + Sp[(size_t)c * Hn];
    }
}

__global__ __launch_bounds__(256) void scan3_kernel(
    const __hip_bfloat16* __restrict__ BC, const float* __restrict__ Av,
    const float* __restrict__ carry, __hip_bfloat16* __restrict__ Y)
{
    int blk = blockIdx.x;
    int hh = (blk & 1) * 256 + threadIdx.x;
    int c = (blk >> 1) & (NCHUNK - 1);
    int b = blk >> 7;
    float a = Av[hh];
    float h = carry[((size_t)b * NCHUNK + c) * Hn + hh];
    const __hip_bfloat16* p = BC + ((size_t)(b * Ln + c * CHUNK) * 1024) + hh;
    __hip_bfloat16* yp = Y + ((size_t)(b * Ln + c * CHUNK) * Hn) + hh;
    #pragma unroll 8
    for (int i = 0; i < CHUNK; ++i) {
        float bv = __bfloat162float(p[(size_t)i * 1024]);
        float cv = __bfloat162float(p[(size_t)i * 1024 + 512]);
        h = a * h + bv;
        yp[(size_t)i * Hn] = __float2bfloat16(cv * h);
    }
}

// ---------------------------------------------------------------- launch
extern "C" void kernel_launch(void* const* d_in, const int* in_sizes, int n_in,
                              void* d_out, int out_size, void* d_ws, size_t ws_size,
                              hipStream_t stream)
{
    const float* x     = (const float*)d_in[0];
    const float* ln_g  = (const float*)d_in[1];
    const float* ln_b  = (const float*)d_in[2];
    const float* W_B   = (const float*)d_in[3];
    const float* b_B   = (const float*)d_in[4];
    const float* W_C   = (const float*)d_in[5];
    const float* b_C   = (const float*)d_in[6];
    const float* W_out = (const float*)d_in[7];
    const float* b_out = (const float*)d_in[8];
    const float* Avec  = (const float*)d_in[9];

    char* ws = (char*)d_ws;
    __hip_bfloat16* WbcT = (__hip_bfloat16*)(ws);                        // 1 MB
    __hip_bfloat16* WoT  = (__hip_bfloat16*)(ws + (1u << 20));           // 0.5 MB
    float*          bbc  = (float*)(ws + (1u << 20) + (1u << 19));       // 4 KB
    __hip_bfloat16* XN   = (__hip_bfloat16*)(ws + (2u << 20));           // 32 MB
    __hip_bfloat16* BC   = (__hip_bfloat16*)(ws + (34u << 20));          // 64 MB
    float*          Sbuf = (float*)(ws + (98u << 20));                   // 1 MB
    float*          Cbuf = (float*)(ws + (99u << 20));                   // 1 MB
    __hip_bfloat16* Y    = (__hip_bfloat16*)(ws + (100u << 20));         // 32 MB

    prep_kernel<<<2048, 256, 0, stream>>>(W_B, W_C, W_out, b_B, b_C, WbcT, WoT, bbc);
    ln_kernel<<<Mrows, 256, 0, stream>>>(x, ln_g, ln_b, XN);
    gemm_kernel<true><<<(Mrows / 128) * (1024 / 128), 256, 0, stream>>>(
        XN, WbcT, bbc, BC, Mrows, 1024);
    scan1_kernel<<<Bn * NCHUNK * 2, 256, 0, stream>>>(BC, Avec, Sbuf);
    scan2_kernel<<<(Bn * Hn) / 256, 256, 0, stream>>>(Sbuf, Avec, Cbuf);
    scan3_kernel<<<Bn * NCHUNK * 2, 256, 0, stream>>>(BC, Avec, Cbuf, Y);
    gemm_kernel<false><<<(Mrows / 128) * (512 / 128), 256, 0, stream>>>(
        Y, WoT, b_out, d_out, Mrows, 512);
}

// Round 2
// 134.525 us; speedup vs baseline: 1.1396x; 1.1396x over previous
//
#include <hip/hip_runtime.h>
#include <hip/hip_bf16.h>
#include <stdint.h>

typedef __bf16 bf16x8 __attribute__((ext_vector_type(8)));
typedef float f32x4 __attribute__((ext_vector_type(4)));

constexpr int Bn = 8, Ln = 4096, Dn = 512, Hn = 512;
constexpr int Mrows = Bn * Ln;                  // 32768
constexpr int CHUNK = 64, NCHUNK = Ln / CHUNK;  // 64 chunks of 64

// ---------------------------------------------------------------- prep
__global__ __launch_bounds__(256) void prep_kernel(
    const float* __restrict__ W_B, const float* __restrict__ W_C,
    const float* __restrict__ W_out, const float* __restrict__ b_B,
    const float* __restrict__ b_C,
    __hip_bfloat16* __restrict__ WbcT, __hip_bfloat16* __restrict__ WoT,
    float* __restrict__ bbc)
{
    int id = blockIdx.x * 256 + threadIdx.x;   // grid covers 1024*512
    {
        int n = id >> 9, k = id & 511;
        float w = (n < Hn) ? W_B[k * Hn + n] : W_C[k * Hn + (n - Hn)];
        WbcT[id] = __float2bfloat16(w);        // WbcT[n][k] = W[k][n]
    }
    if (id < Hn * Hn) {
        int n = id >> 9, k = id & 511;
        WoT[id] = __float2bfloat16(W_out[k * Hn + n]);
    }
    if (id < 2 * Hn) bbc[id] = (id < Hn) ? b_B[id] : b_C[id - Hn];
}

// ---------------------------------------------------------------- layernorm
__global__ __launch_bounds__(256) void ln_kernel(
    const float* __restrict__ x, const float* __restrict__ gamma,
    const float* __restrict__ beta, __hip_bfloat16* __restrict__ xn)
{
    int row = blockIdx.x;
    const float2* xr = reinterpret_cast<const float2*>(x + (size_t)row * Dn);
    int t = threadIdx.x;
    float2 v = xr[t];
    float s = v.x + v.y;
    float s2 = v.x * v.x + v.y * v.y;
    #pragma unroll
    for (int off = 32; off; off >>= 1) {
        s  += __shfl_down(s, off);
        s2 += __shfl_down(s2, off);
    }
    __shared__ float ps[4], ps2[4];
    int wid = t >> 6, lane = t & 63;
    if (lane == 0) { ps[wid] = s; ps2[wid] = s2; }
    __syncthreads();
    float su = ps[0] + ps[1] + ps[2] + ps[3];
    float su2 = ps2[0] + ps2[1] + ps2[2] + ps2[3];
    float mu = su * (1.0f / Dn);
    float var = su2 * (1.0f / Dn) - mu * mu;
    float inv = rsqrtf(var + 1e-5f);
    int c0 = 2 * t;
    float y0 = (v.x - mu) * inv * gamma[c0]     + beta[c0];
    float y1 = (v.y - mu) * inv * gamma[c0 + 1] + beta[c0 + 1];
    __hip_bfloat162 o;
    o.x = __float2bfloat16(y0);
    o.y = __float2bfloat16(y1);
    reinterpret_cast<__hip_bfloat162*>(xn + (size_t)row * Dn)[t] = o;
}

// ---------------------------------------------------------------- 8-phase 256^2 GEMM
// C[M][NT] = A[M][512] * BT[NT][512]^T + bias.  BM=BN=256, BK=64, 8 waves.
// LDS 128KB: buf(kt&1) { A: 2 halves of [128][64], B: same }, XOR-swizzled
// slot' = slot ^ (row&7) on read, pre-swizzled global source for gload_lds.
template <int NT, bool OUT_BF16>
__global__ __launch_bounds__(512, 2) void gemm8_kernel(
    const __hip_bfloat16* __restrict__ A,
    const __hip_bfloat16* __restrict__ BT,
    const float* __restrict__ bias,
    void* __restrict__ Cout)
{
    constexpr int K = 512, NKT = K / 64, NIT = NKT / 2;
    extern __shared__ unsigned short lds[];    // 65536 shorts = 128 KB

    int nwg = gridDim.x, bid = blockIdx.x;
    int bswz = (bid & 7) * (nwg >> 3) + (bid >> 3);   // XCD swizzle (nwg%8==0)
    constexpr int NBN = NT / 256;
    int bm = bswz / NBN, bnb = bswz % NBN;
    int row0 = bm * 256, col0 = bnb * 256;

    int tid = threadIdx.x;
    int w = tid >> 6, l = tid & 63;
    int rl = l & 15, qg = l >> 4, sx = l & 7, r8 = l >> 3;

    // staging: per-lane pre-swizzled global base (rule #21: linear LDS dest)
    int scol = (sx ^ r8) * 8;
    const __hip_bfloat16* gA = A  + (size_t)(row0 + w * 16 + r8) * K + scol;
    const __hip_bfloat16* gB = BT + (size_t)(col0 + w * 16 + r8) * K + scol;

    // LDS shorts layout: buf*32768 + (B?16384:0) + half*8192 + row*64 + slot*8
#define LDSA(b, h) (&lds[(b) * 32768 + (h) * 8192 + w * 1024])
#define LDSB(b, h) (&lds[(b) * 32768 + 16384 + (h) * 8192 + w * 1024])
#define GLDS(src, dst) __builtin_amdgcn_global_load_lds( \
        (const __attribute__((address_space(1))) void*)(const void*)(src), \
        (__attribute__((address_space(3))) void*)(void*)(dst), 16, 0, 0)
#define STAGE_A(b, kt, h) { \
        GLDS(gA + (size_t)((h) * 128) * K + (kt) * 64, LDSA(b, h)); \
        GLDS(gA + (size_t)((h) * 128 + 8) * K + (kt) * 64, LDSA(b, h) + 512); }
#define STAGE_B(b, kt, h) { \
        GLDS(gB + (size_t)((h) * 128) * K + (kt) * 64, LDSB(b, h)); \
        GLDS(gB + (size_t)((h) * 128 + 8) * K + (kt) * 64, LDSB(b, h) + 512); }
#define BARRIER { asm volatile("" ::: "memory"); __builtin_amdgcn_s_barrier(); \
                  asm volatile("" ::: "memory"); }
#define VMCNT(n) asm volatile("s_waitcnt vmcnt(" #n ")" ::: "memory")

    int aoff = (w >> 2) * 8192 + rl * 64;
    int boff = 16384 + ((w & 3) >> 1) * 8192 + (((w & 3) & 1) * 64 + rl) * 64;
    int s0 = (qg ^ sx) * 8;                  // kk=0 slot offset; kk=1 -> s0^32

    f32x4 acc[8][4] = {};
    bf16x8 af[4][2], bfr[4][2];

#define RD_A(mq, b) { _Pragma("unroll") for (int i2 = 0; i2 < 4; ++i2) { \
        af[i2][0] = *(const bf16x8*)&lds[(b) * 32768 + aoff + ((mq) * 4 + i2) * 1024 + s0]; \
        af[i2][1] = *(const bf16x8*)&lds[(b) * 32768 + aoff + ((mq) * 4 + i2) * 1024 + (s0 ^ 32)]; } }
#define RD_B(nh, b) { _Pragma("unroll") for (int j2 = 0; j2 < 2; ++j2) { \
        bfr[(nh) * 2 + j2][0] = *(const bf16x8*)&lds[(b) * 32768 + boff + ((nh) * 2 + j2) * 1024 + s0]; \
        bfr[(nh) * 2 + j2][1] = *(const bf16x8*)&lds[(b) * 32768 + boff + ((nh) * 2 + j2) * 1024 + (s0 ^ 32)]; } }
#define MM(mq, nq) { __builtin_amdgcn_s_setprio(1); \
        _Pragma("unroll") for (int i2 = 0; i2 < 4; ++i2) \
        _Pragma("unroll") for (int n2 = 0; n2 < 2; ++n2) \
        _Pragma("unroll") for (int kk = 0; kk < 2; ++kk) \
            acc[(mq) * 4 + i2][(nq) * 2 + n2] = __builtin_amdgcn_mfma_f32_16x16x32_bf16( \
                af[i2][kk], bfr[(nq) * 2 + n2][kk], acc[(mq) * 4 + i2][(nq) * 2 + n2], 0, 0, 0); \
        __builtin_amdgcn_s_setprio(0); }

    // prologue: kt0 {B0,B1,A0,A1} + kt1 {B0,B1,A0} = 7 half-tiles (14 loads)
    STAGE_B(0, 0, 0); STAGE_B(0, 0, 1); STAGE_A(0, 0, 0); STAGE_A(0, 0, 1);
    STAGE_B(1, 1, 0); STAGE_B(1, 1, 1); STAGE_A(1, 1, 0);
    VMCNT(6);          // kt0 landed, 3 half-tiles in flight
    BARRIER;

    for (int it = 0; it < NIT; ++it) {
        int ktB = 2 * it + 1, ktN = 2 * it + 2;
        bool more = (it < NIT - 1);
        // ph1  Q(0,0) on buf0 (kt=2it)
        RD_A(0, 0); RD_B(0, 0);
        STAGE_A(1, ktB, 1);                    // kt(2it+1).A1 — always valid
        BARRIER; MM(0, 0); BARRIER;
        // ph2  Q(0,1)
        RD_B(1, 0);
        if (more) STAGE_B(0, ktN, 0);
        BARRIER; MM(0, 1); BARRIER;
        // ph3  Q(1,1)
        RD_A(1, 0);
        if (more) STAGE_B(0, ktN, 1);
        BARRIER; MM(1, 1); BARRIER;
        // ph4  Q(1,0)  — vmcnt gate for kt(2it+1)
        if (more) STAGE_A(0, ktN, 0);
        BARRIER; MM(1, 0);
        if (more) { VMCNT(6); } else { VMCNT(0); }
        BARRIER;
        // ph5  Q(0,0) on buf1 (kt=2it+1)
        RD_A(0, 1); RD_B(0, 1);
        if (more) STAGE_A(0, ktN, 1);
        BARRIER; MM(0, 0); BARRIER;
        // ph6  Q(0,1)
        RD_B(1, 1);
        if (more) STAGE_B(1, ktN + 1, 0);
        BARRIER; MM(0, 1); BARRIER;
        // ph7  Q(1,1)
        RD_A(1, 1);
        if (more) STAGE_B(1, ktN + 1, 1);
        BARRIER; MM(1, 1); BARRIER;
        // ph8  Q(1,0) — vmcnt gate for kt(2it+2)
        if (more) {
            STAGE_A(1, ktN + 1, 0);
            BARRIER; MM(1, 0); VMCNT(6); BARRIER;
        } else {
            MM(1, 0);
        }
    }

    // epilogue: C = acc + bias
    int crow0 = row0 + (w >> 2) * 128 + qg * 4;
    int ccol0 = col0 + (w & 3) * 64 + rl;
    #pragma unroll
    for (int n = 0; n < 4; ++n) {
        float bv = bias[ccol0 + n * 16];
        #pragma unroll
        for (int i = 0; i < 8; ++i) {
            #pragma unroll
            for (int j = 0; j < 4; ++j) {
                float v = acc[i][n][j] + bv;
                size_t idx = (size_t)(crow0 + i * 16 + j) * NT + (ccol0 + n * 16);
                if (OUT_BF16)
                    ((__hip_bfloat16*)Cout)[idx] = __float2bfloat16(v);
                else
                    ((float*)Cout)[idx] = v;
            }
        }
    }
#undef LDSA
#undef LDSB
#undef GLDS
#undef STAGE_A
#undef STAGE_B
#undef BARRIER
#undef VMCNT
#undef RD_A
#undef RD_B
#undef MM
}

// ---------------------------------------------------------------- scan
// BC layout: [row][1024] bf16, Bt = cols 0..511, Ct = cols 512..1023
__global__ __launch_bounds__(256) void scan1_kernel(
    const __hip_bfloat16* __restrict__ BC, const float* __restrict__ Av,
    float* __restrict__ S)
{
    int blk = blockIdx.x;                       // Bn*NCHUNK*2 = 1024
    int hh = (blk & 1) * 256 + threadIdx.x;
    int c = (blk >> 1) & (NCHUNK - 1);
    int b = blk >> 7;
    float a = Av[hh];
    const __hip_bfloat16* p = BC + ((size_t)(b * Ln + c * CHUNK) * 1024) + hh;
    float s = 0.f;
    #pragma unroll 8
    for (int i = 0; i < CHUNK; ++i) {
        float bv = __bfloat162float(p[(size_t)i * 1024]);
        s = a * s + bv;
    }
    S[((size_t)b * NCHUNK + c) * Hn + hh] = s;
}

__global__ __launch_bounds__(256) void scan2_kernel(
    const float* __restrict__ S, const float* __restrict__ Av,
    float* __restrict__ carry)
{
    int id = blockIdx.x * 256 + threadIdx.x;    // Bn*Hn = 4096
    int hh = id & (Hn - 1), b = id >> 9;
    float a = Av[hh];
    float aG = a;
    #pragma unroll
    for (int i = 0; i < 6; ++i) aG *= aG;       // a^64
    float h = 0.f;
    const float* Sp = S + (size_t)b * NCHUNK * Hn + hh;
    float* cp = carry + (size_t)b * NCHUNK * Hn + hh;
    for (int c = 0; c < NCHUNK; ++c) {
        cp[(size_t)c * Hn] = h;                 // state entering chunk c
        h = aG * h + Sp[(size_t)c * Hn];
    }
}

__global__ __launch_bounds__(256) void scan3_kernel(
    const __hip_bfloat16* __restrict__ BC, const float* __restrict__ Av,
    const float* __restrict__ carry, __hip_bfloat16* __restrict__ Y)
{
    int blk = blockIdx.x;
    int hh = (blk & 1) * 256 + threadIdx.x;
    int c = (blk >> 1) & (NCHUNK - 1);
    int b = blk >> 7;
    float a = Av[hh];
    float h = carry[((size_t)b * NCHUNK + c) * Hn + hh];
    const __hip_bfloat16* p = BC + ((size_t)(b * Ln + c * CHUNK) * 1024) + hh;
    __hip_bfloat16* yp = Y + ((size_t)(b * Ln + c * CHUNK) * Hn) + hh;
    #pragma unroll 8
    for (int i = 0; i < CHUNK; ++i) {
        float bv = __bfloat162float(p[(size_t)i * 1024]);
        float cv = __bfloat162float(p[(size_t)i * 1024 + 512]);
        h = a * h + bv;
        yp[(size_t)i * Hn] = __float2bfloat16(cv * h);
    }
}

// ---------------------------------------------------------------- launch
extern "C" void kernel_launch(void* const* d_in, const int* in_sizes, int n_in,
                              void* d_out, int out_size, void* d_ws, size_t ws_size,
                              hipStream_t stream)
{
    const float* x     = (const float*)d_in[0];
    const float* ln_g  = (const float*)d_in[1];
    const float* ln_b  = (const float*)d_in[2];
    const float* W_B   = (const float*)d_in[3];
    const float* b_B   = (const float*)d_in[4];
    const float* W_C   = (const float*)d_in[5];
    const float* b_C   = (const float*)d_in[6];
    const float* W_out = (const float*)d_in[7];
    const float* b_out = (const float*)d_in[8];
    const float* Avec  = (const float*)d_in[9];

    char* ws = (char*)d_ws;
    __hip_bfloat16* WbcT = (__hip_bfloat16*)(ws);                        // 1 MB
    __hip_bfloat16* WoT  = (__hip_bfloat16*)(ws + (1u << 20));           // 0.5 MB
    float*          bbc  = (float*)(ws + (1u << 20) + (1u << 19));       // 4 KB
    __hip_bfloat16* XN   = (__hip_bfloat16*)(ws + (2u << 20));           // 32 MB
    __hip_bfloat16* BC   = (__hip_bfloat16*)(ws + (34u << 20));          // 64 MB
    float*          Sbuf = (float*)(ws + (98u << 20));                   // 1 MB
    float*          Cbuf = (float*)(ws + (99u << 20));                   // 1 MB
    __hip_bfloat16* Y    = (__hip_bfloat16*)(ws + (100u << 20));         // 32 MB

    hipFuncSetAttribute((const void*)gemm8_kernel<1024, true>,
                        hipFuncAttributeMaxDynamicSharedMemorySize, 131072);
    hipFuncSetAttribute((const void*)gemm8_kernel<512, false>,
                        hipFuncAttributeMaxDynamicSharedMemorySize, 131072);

    prep_kernel<<<2048, 256, 0, stream>>>(W_B, W_C, W_out, b_B, b_C, WbcT, WoT, bbc);
    ln_kernel<<<Mrows, 256, 0, stream>>>(x, ln_g, ln_b, XN);
    gemm8_kernel<1024, true><<<(Mrows / 256) * (1024 / 256), 512, 131072, stream>>>(
        XN, WbcT, bbc, BC);
    scan1_kernel<<<Bn * NCHUNK * 2, 256, 0, stream>>>(BC, Avec, Sbuf);
    scan2_kernel<<<(Bn * Hn) / 256, 256, 0, stream>>>(Sbuf, Avec, Cbuf);
    scan3_kernel<<<Bn * NCHUNK * 2, 256, 0, stream>>>(BC, Avec, Cbuf, Y);
    gemm8_kernel<512, false><<<(Mrows / 256) * (512 / 256), 512, 131072, stream>>>(
        Y, WoT, b_out, d_out);
}